// Round 5
// baseline (16725.098 us; speedup 1.0000x reference)
//
#include <hip/hip_runtime.h>
#include <hip/hip_bf16.h>
#include <math.h>

// ---------------------------------------------------------------------------
// Classifier_with_Augmentation: NTS-Net-style pipeline.
//  outputs (flat float32 in d_out):
//   labels 16x200 @0 | win_scores 16x7 @3200 | win_logits 112x200 @3312
//   indices 16x7 @25712 | all_scores 16x602 @25824 | coordinates 16x7x4 @35456
// ---------------------------------------------------------------------------

#define OFF_LAB 0
#define OFF_WSC 3200
#define OFF_LOG 3312
#define OFF_IDX 25712
#define OFF_ALL 25824
#define OFF_CRD 35456

#define BS 256
#define CO4 4  // output channels per thread

static inline int cdiv(int a, int b) { return (a + b - 1) / b; }

// ---- window geometry ------------------------------------------------------
__device__ __forceinline__ void win_decode(int w, int& rh, int& rw, int& r, int& c) {
  const int RH[6] = {4, 3, 5, 6, 5, 7};
  const int RW[6] = {4, 5, 3, 6, 7, 5};
  int rem = w;
#pragma unroll
  for (int i = 0; i < 6; ++i) {
    int nc = 15 - RW[i];
    int cnt = (15 - RH[i]) * nc;
    if (rem < cnt) { rh = RH[i]; rw = RW[i]; r = rem / nc; c = rem - (rem / nc) * nc; return; }
    rem -= cnt;
  }
  rh = 4; rw = 4; r = 0; c = 0;
}

__device__ __forceinline__ void win_to_box(int w, float* bb) {
  int rh, rw, r, c;
  win_decode(w, rh, rw, r, c);
  bb[0] = r * 32.f;
  bb[1] = c * 32.f;
  bb[2] = (r + rh) * 32.f - 1.f;
  bb[3] = (c + rw) * 32.f - 1.f;
}

// ---- window scores --------------------------------------------------------
__global__ void winscores_kernel(const float* __restrict__ att, float* __restrict__ s_all,
                                 float* __restrict__ out) {
  int idx = blockIdx.x * blockDim.x + threadIdx.x;
  if (idx >= 16 * 602) return;
  int b = idx / 602, w = idx - b * 602;
  int rh, rw, r, c;
  win_decode(w, rh, rw, r, c);
  const float* a = att + b * 196;
  float s = 0.f;
  for (int dr = 0; dr < rh; ++dr)
    for (int dc = 0; dc < rw; ++dc)
      s += a[(r + dr) * 14 + (c + dc)];
  float v = s / (float)(rh * rw);
  s_all[idx] = v;
  out[OFF_ALL + idx] = v;
}

// ---- NMS: one wave per (batch, group) -------------------------------------
__global__ void nms_kernel(const float* __restrict__ s_all, int* __restrict__ idx_i) {
  const int b = blockIdx.x, g = blockIdx.y;
  const int gs = g ? 361 : 0;
  const int cnt = g ? 241 : 361;
  const int nsel = g ? 3 : 4;
  const int obase = b * 7 + (g ? 4 : 0);
  __shared__ float sc[361];
  __shared__ float bx0[361], bx1[361], bx2[361], bx3[361];
  const int tid = threadIdx.x;
  for (int k = tid; k < cnt; k += 64) {
    sc[k] = s_all[b * 602 + gs + k];
    float bb[4];
    win_to_box(gs + k, bb);
    bx0[k] = bb[0]; bx1[k] = bb[1]; bx2[k] = bb[2]; bx3[k] = bb[3];
  }
  __syncthreads();
  for (int it = 0; it < nsel; ++it) {
    float bv = -INFINITY;
    int bi = 0x7fffffff;
    for (int k = tid; k < cnt; k += 64) {
      float v = sc[k];
      if (v > bv || (v == bv && k < bi)) { bv = v; bi = k; }
    }
#pragma unroll
    for (int off = 32; off > 0; off >>= 1) {
      float ov = __shfl_down(bv, off);
      int oi = __shfl_down(bi, off);
      if (ov > bv || (ov == bv && oi < bi)) { bv = ov; bi = oi; }
    }
    bi = __shfl(bi, 0);
    if (tid == 0) idx_i[obase + it] = gs + bi;
    float X0 = bx0[bi], X1 = bx1[bi], X2 = bx2[bi], X3 = bx3[bi];
    float a1 = (X2 - X0 + 1.f) * (X3 - X1 + 1.f);
    __syncthreads();
    for (int k = tid; k < cnt; k += 64) {
      float x0 = fmaxf(X0, bx0[k]);
      float y0 = fmaxf(X1, bx1[k]);
      float x1 = fminf(X2, bx2[k]);
      float y1 = fminf(X3, bx3[k]);
      float inter = fmaxf(x1 - x0 + 1.f, 0.f) * fmaxf(y1 - y0 + 1.f, 0.f);
      float a2 = (bx2[k] - bx0[k] + 1.f) * (bx3[k] - bx1[k] + 1.f);
      float iou = inter / (a1 + a2 - inter);
      if (iou > 0.25f) sc[k] = -INFINITY;
    }
    if (tid == 0) sc[bi] = -INFINITY;
    __syncthreads();
  }
}

// ---- gather ---------------------------------------------------------------
__global__ void gather_kernel(const int* __restrict__ idx_i, const float* __restrict__ s_all,
                              float* __restrict__ boxes, float* __restrict__ out) {
  int t = blockIdx.x * blockDim.x + threadIdx.x;
  if (t >= 112) return;
  int b = t / 7;
  int w = idx_i[t];
  out[OFF_IDX + t] = (float)w;
  out[OFF_WSC + t] = s_all[b * 602 + w];
  float bb[4];
  win_to_box(w, bb);
#pragma unroll
  for (int k = 0; k < 4; ++k) {
    boxes[t * 4 + k] = bb[k];
    out[OFF_CRD + t * 4 + k] = bb[k];
  }
}

// ---- bilinear crop-resize 448 -> 112 --------------------------------------
__global__ void crop_resize_kernel(const float* __restrict__ x, const float* __restrict__ boxes,
                                   float* __restrict__ wimgs) {
  int idx = blockIdx.x * blockDim.x + threadIdx.x;
  const int total = 112 * 3 * 112 * 112;
  if (idx >= total) return;
  int j = idx % 112;
  int i = (idx / 112) % 112;
  int ch = (idx / (112 * 112)) % 3;
  int bp = idx / (3 * 112 * 112);
  int b = bp / 7;
  const float* bx = boxes + bp * 4;
  float t_i = (float)i / 111.0f;
  float t_j = (float)j / 111.0f;
  float rs = bx[0] + (bx[2] - bx[0]) * t_i;
  float cs = bx[1] + (bx[3] - bx[1]) * t_j;
  float r0f = floorf(rs), c0f = floorf(cs);
  float wr = rs - r0f, wc = cs - c0f;
  int r0 = (int)r0f, c0 = (int)c0f;
  int r1 = min(r0 + 1, 447), c1 = min(c0 + 1, 447);
  const float* img = x + ((size_t)b * 3 + ch) * 448 * 448;
  float v00 = img[r0 * 448 + c0], v01 = img[r0 * 448 + c1];
  float v10 = img[r1 * 448 + c0], v11 = img[r1 * 448 + c1];
  float top = (1.f - wc) * v00 + wc * v01;
  float bot = (1.f - wc) * v10 + wc * v11;
  wimgs[idx] = (1.f - wr) * top + wr * bot;
}

// ---- conv 3x3 stride2 SAME + bias + relu, CO4 channels per thread ---------
// One output pixel per thread (round-1 mapping & guards), 4 co per thread.
// grid.x = Cout/CO4 (fastest -> co-groups schedule-adjacent -> L2 input reuse)
// grid.y = cdiv(N*Hout*Wout, 256)
// Weights staged in LDS transposed [ci][k][co0..3] in 64-ci chunks (9.2KB),
// read as broadcast float4 (b128, all lanes same address -> conflict-free).
__global__ void conv4_kernel(const float* __restrict__ in, const float* __restrict__ wt,
                             const float* __restrict__ bias, float* __restrict__ out,
                             int N, int Cin, int Hin, int Win, int Hout, int Wout, int pad) {
  const int co0 = blockIdx.x * CO4;
  const int Cout = gridDim.x * CO4;
  const int HW = Hout * Wout;
  const int total = N * HW;
  const int lin = blockIdx.y * 256 + threadIdx.x;
  const bool active = lin < total;
  int n = 0, pix = 0;
  if (active) { n = lin / HW; pix = lin - n * HW; }
  const int oh = pix / Wout, ow = pix - (pix / Wout) * Wout;
  const int ih0 = 2 * oh - pad, iw0 = 2 * ow - pad;
  const size_t inplane = (size_t)Hin * Win;
  const float* nbase = in + (size_t)n * Cin * inplane;
  const bool interior = active && (ih0 >= 0) && (iw0 >= 0) && (ih0 + 2 < Hin) && (iw0 + 2 < Win);

  float acc0 = 0.f, acc1 = 0.f, acc2 = 0.f, acc3 = 0.f;
  __shared__ float wlds[64 * 9 * CO4];  // [ci][k][co], 9216B

  const int nchunk = (Cin + 63) >> 6;
  for (int ch = 0; ch < nchunk; ++ch) {
    const int ci0 = ch << 6;
    const int cich = min(64, Cin - ci0);
    const int nel = cich * 9;
    for (int t = threadIdx.x; t < nel * CO4; t += 256) {
      int co = t / nel;
      int rem = t - co * nel;  // rem = ci*9+k, contiguous in global
      wlds[rem * CO4 + co] = wt[(size_t)(co0 + co) * Cin * 9 + (size_t)ci0 * 9 + rem];
    }
    __syncthreads();
    if (interior) {
      const float* base = nbase + (size_t)ci0 * inplane + (size_t)ih0 * Win + iw0;
      for (int ci = 0; ci < cich; ++ci) {
        const float* p = base + (size_t)ci * inplane;
        float v[9];
        v[0] = p[0]; v[1] = p[1]; v[2] = p[2];
        v[3] = p[Win]; v[4] = p[Win + 1]; v[5] = p[Win + 2];
        v[6] = p[2 * Win]; v[7] = p[2 * Win + 1]; v[8] = p[2 * Win + 2];
        const int b9 = ci * 9;
#pragma unroll
        for (int k = 0; k < 9; ++k) {
          float4 w4 = *(const float4*)&wlds[(b9 + k) * CO4];
          acc0 = fmaf(v[k], w4.x, acc0);
          acc1 = fmaf(v[k], w4.y, acc1);
          acc2 = fmaf(v[k], w4.z, acc2);
          acc3 = fmaf(v[k], w4.w, acc3);
        }
      }
    } else if (active) {
      for (int ci = 0; ci < cich; ++ci) {
        const float* p = nbase + (size_t)(ci0 + ci) * inplane;
        const int b9 = ci * 9;
#pragma unroll
        for (int kh = 0; kh < 3; ++kh) {
          int ih = ih0 + kh;
          if ((unsigned)ih >= (unsigned)Hin) continue;
#pragma unroll
          for (int kw = 0; kw < 3; ++kw) {
            int iw = iw0 + kw;
            if ((unsigned)iw >= (unsigned)Win) continue;
            float vv = p[(size_t)ih * Win + iw];
            float4 w4 = *(const float4*)&wlds[(b9 + kh * 3 + kw) * CO4];
            acc0 = fmaf(vv, w4.x, acc0);
            acc1 = fmaf(vv, w4.y, acc1);
            acc2 = fmaf(vv, w4.z, acc2);
            acc3 = fmaf(vv, w4.w, acc3);
          }
        }
      }
    }
    __syncthreads();
  }
  if (!active) return;
  float* ob = out + ((size_t)n * Cout + co0) * HW + pix;
  ob[0] = fmaxf(acc0 + bias[co0 + 0], 0.f);
  ob[HW] = fmaxf(acc1 + bias[co0 + 1], 0.f);
  ob[2 * (size_t)HW] = fmaxf(acc2 + bias[co0 + 2], 0.f);
  ob[3 * (size_t)HW] = fmaxf(acc3 + bias[co0 + 3], 0.f);
}

// ---- mean pool ------------------------------------------------------------
__global__ void avgpool_kernel(const float* __restrict__ feat, float* __restrict__ pooled,
                               int M, int C, int S) {
  int idx = blockIdx.x * blockDim.x + threadIdx.x;
  if (idx >= M * C) return;
  const float* p = feat + (size_t)idx * S;
  float s = 0.f;
  for (int i = 0; i < S; ++i) s += p[i];
  pooled[idx] = s / (float)S;
}

// ---- head GEMM ------------------------------------------------------------
__global__ void head_kernel(const float* __restrict__ pooled, const float* __restrict__ hw,
                            const float* __restrict__ hb, float* __restrict__ outp, int M) {
  int idx = blockIdx.x * blockDim.x + threadIdx.x;
  if (idx >= M * 200) return;
  int m = idx / 200, c = idx - m * 200;
  float acc = hb[c];
  const float* pm = pooled + m * 512;
  for (int k = 0; k < 512; ++k) acc = fmaf(pm[k], hw[k * 200 + c], acc);
  outp[idx] = acc;
}

// ---------------------------------------------------------------------------
static void launch_conv4(const float* in, const float* wt, const float* bias, float* out,
                         int N, int Cin, int Hin, int Hout, int Cout, int pad, hipStream_t s) {
  int total = N * Hout * Hout;
  dim3 grid(Cout / CO4, cdiv(total, 256));
  conv4_kernel<<<grid, 256, 0, s>>>(in, wt, bias, out, N, Cin, Hin, Hin, Hout, Hout, pad);
}

extern "C" void kernel_launch(void* const* d_in, const int* in_sizes, int n_in,
                              void* d_out, int out_size, void* d_ws, size_t ws_size,
                              hipStream_t stream) {
  const float* x = (const float*)d_in[0];
  const float* att = (const float*)d_in[1];
  const float* W[5] = {(const float*)d_in[2], (const float*)d_in[4], (const float*)d_in[6],
                       (const float*)d_in[8], (const float*)d_in[10]};
  const float* Bv[5] = {(const float*)d_in[3], (const float*)d_in[5], (const float*)d_in[7],
                        (const float*)d_in[9], (const float*)d_in[11]};
  const float* head_w = (const float*)d_in[12];
  const float* head_b = (const float*)d_in[13];
  float* out = (float*)d_out;
  float* ws = (float*)d_ws;

  // workspace layout (floats), ~104MB (round-1 proven)
  size_t o = 0;
  float* s_all = ws + o;  o += 16 * 602;
  int* idx_i = (int*)(ws + o); o += 112;
  float* boxes = ws + o;  o += 112 * 4;
  float* wimgs = ws + o;  o += (size_t)112 * 3 * 112 * 112;
  float* featB = ws + o;  o += (size_t)16 * 512 * 196;
  float* featC = ws + o;  o += (size_t)112 * 512 * 16;
  float* pooled = ws + o; o += (size_t)112 * 512;
  float* bufA = ws + o;   o += (size_t)4 * 64 * 224 * 224;
  float* bufB = ws + o;   o += (size_t)4 * 128 * 112 * 112;

  // ---- proposal path ----
  winscores_kernel<<<cdiv(16 * 602, BS), BS, 0, stream>>>(att, s_all, out);
  nms_kernel<<<dim3(16, 2), 64, 0, stream>>>(s_all, idx_i);
  gather_kernel<<<1, 128, 0, stream>>>(idx_i, s_all, boxes, out);
  crop_resize_kernel<<<cdiv(112 * 3 * 112 * 112, BS), BS, 0, stream>>>(x, boxes, wimgs);

  // ---- big encoder: 4-image chunks (round-1 structure) ----
  for (int chunk = 0; chunk < 4; ++chunk) {
    int n0 = chunk * 4;
    const float* in0 = x + (size_t)n0 * 3 * 448 * 448;
    launch_conv4(in0, W[0], Bv[0], bufA, 4, 3, 448, 224, 64, 0, stream);
    launch_conv4(bufA, W[1], Bv[1], bufB, 4, 64, 224, 112, 128, 0, stream);
    launch_conv4(bufB, W[2], Bv[2], bufA, 4, 128, 112, 56, 256, 0, stream);
    launch_conv4(bufA, W[3], Bv[3], bufB, 4, 256, 56, 28, 512, 0, stream);
    launch_conv4(bufB, W[4], Bv[4], featB + (size_t)n0 * 512 * 196, 4, 512, 28, 14, 512, 0,
                 stream);
  }
  avgpool_kernel<<<cdiv(16 * 512, BS), BS, 0, stream>>>(featB, pooled, 16, 512, 196);
  head_kernel<<<cdiv(16 * 200, BS), BS, 0, stream>>>(pooled, head_w, head_b, out + OFF_LAB, 16);

  // ---- crop encoder: 56-crop chunks (round-1 structure) ----
  for (int chunk = 0; chunk < 2; ++chunk) {
    int c0 = chunk * 56;
    const float* in0 = wimgs + (size_t)c0 * 3 * 112 * 112;
    launch_conv4(in0, W[0], Bv[0], bufA, 56, 3, 112, 56, 64, 0, stream);
    launch_conv4(bufA, W[1], Bv[1], bufB, 56, 64, 56, 28, 128, 0, stream);
    launch_conv4(bufB, W[2], Bv[2], bufA, 56, 128, 28, 14, 256, 0, stream);
    launch_conv4(bufA, W[3], Bv[3], bufB, 56, 256, 14, 7, 512, 0, stream);
    launch_conv4(bufB, W[4], Bv[4], featC + (size_t)c0 * 512 * 16, 56, 512, 7, 4, 512, 1, stream);
  }
  avgpool_kernel<<<cdiv(112 * 512, BS), BS, 0, stream>>>(featC, pooled, 112, 512, 16);
  head_kernel<<<cdiv(112 * 200, BS), BS, 0, stream>>>(pooled, head_w, head_b, out + OFF_LOG, 112);
}

// Round 6
// 14110.869 us; speedup vs baseline: 1.1853x; 1.1853x over previous
//
#include <hip/hip_runtime.h>
#include <hip/hip_bf16.h>
#include <math.h>

// ---------------------------------------------------------------------------
// Classifier_with_Augmentation: NTS-Net-style pipeline.
//  outputs (flat float32 in d_out):
//   labels 16x200 @0 | win_scores 16x7 @3200 | win_logits 112x200 @3312
//   indices 16x7 @25712 | all_scores 16x602 @25824 | coordinates 16x7x4 @35456
// ---------------------------------------------------------------------------

#define OFF_LAB 0
#define OFF_WSC 3200
#define OFF_LOG 3312
#define OFF_IDX 25712
#define OFF_ALL 25824
#define OFF_CRD 35456

#define BS 256
#define CO4 4  // output channels per thread

static inline int cdiv(int a, int b) { return (a + b - 1) / b; }

// ---- window geometry ------------------------------------------------------
__device__ __forceinline__ void win_decode(int w, int& rh, int& rw, int& r, int& c) {
  const int RH[6] = {4, 3, 5, 6, 5, 7};
  const int RW[6] = {4, 5, 3, 6, 7, 5};
  int rem = w;
#pragma unroll
  for (int i = 0; i < 6; ++i) {
    int nc = 15 - RW[i];
    int cnt = (15 - RH[i]) * nc;
    if (rem < cnt) { rh = RH[i]; rw = RW[i]; r = rem / nc; c = rem - (rem / nc) * nc; return; }
    rem -= cnt;
  }
  rh = 4; rw = 4; r = 0; c = 0;
}

__device__ __forceinline__ void win_to_box(int w, float* bb) {
  int rh, rw, r, c;
  win_decode(w, rh, rw, r, c);
  bb[0] = r * 32.f;
  bb[1] = c * 32.f;
  bb[2] = (r + rh) * 32.f - 1.f;
  bb[3] = (c + rw) * 32.f - 1.f;
}

// ---- window scores --------------------------------------------------------
__global__ void winscores_kernel(const float* __restrict__ att, float* __restrict__ s_all,
                                 float* __restrict__ out) {
  int idx = blockIdx.x * blockDim.x + threadIdx.x;
  if (idx >= 16 * 602) return;
  int b = idx / 602, w = idx - b * 602;
  int rh, rw, r, c;
  win_decode(w, rh, rw, r, c);
  const float* a = att + b * 196;
  float s = 0.f;
  for (int dr = 0; dr < rh; ++dr)
    for (int dc = 0; dc < rw; ++dc)
      s += a[(r + dr) * 14 + (c + dc)];
  float v = s / (float)(rh * rw);
  s_all[idx] = v;
  out[OFF_ALL + idx] = v;
}

// ---- NMS: one wave per (batch, group) -------------------------------------
__global__ void nms_kernel(const float* __restrict__ s_all, int* __restrict__ idx_i) {
  const int b = blockIdx.x, g = blockIdx.y;
  const int gs = g ? 361 : 0;
  const int cnt = g ? 241 : 361;
  const int nsel = g ? 3 : 4;
  const int obase = b * 7 + (g ? 4 : 0);
  __shared__ float sc[361];
  __shared__ float bx0[361], bx1[361], bx2[361], bx3[361];
  const int tid = threadIdx.x;
  for (int k = tid; k < cnt; k += 64) {
    sc[k] = s_all[b * 602 + gs + k];
    float bb[4];
    win_to_box(gs + k, bb);
    bx0[k] = bb[0]; bx1[k] = bb[1]; bx2[k] = bb[2]; bx3[k] = bb[3];
  }
  __syncthreads();
  for (int it = 0; it < nsel; ++it) {
    float bv = -INFINITY;
    int bi = 0x7fffffff;
    for (int k = tid; k < cnt; k += 64) {
      float v = sc[k];
      if (v > bv || (v == bv && k < bi)) { bv = v; bi = k; }
    }
#pragma unroll
    for (int off = 32; off > 0; off >>= 1) {
      float ov = __shfl_down(bv, off);
      int oi = __shfl_down(bi, off);
      if (ov > bv || (ov == bv && oi < bi)) { bv = ov; bi = oi; }
    }
    bi = __shfl(bi, 0);
    if (tid == 0) idx_i[obase + it] = gs + bi;
    float X0 = bx0[bi], X1 = bx1[bi], X2 = bx2[bi], X3 = bx3[bi];
    float a1 = (X2 - X0 + 1.f) * (X3 - X1 + 1.f);
    __syncthreads();
    for (int k = tid; k < cnt; k += 64) {
      float x0 = fmaxf(X0, bx0[k]);
      float y0 = fmaxf(X1, bx1[k]);
      float x1 = fminf(X2, bx2[k]);
      float y1 = fminf(X3, bx3[k]);
      float inter = fmaxf(x1 - x0 + 1.f, 0.f) * fmaxf(y1 - y0 + 1.f, 0.f);
      float a2 = (bx2[k] - bx0[k] + 1.f) * (bx3[k] - bx1[k] + 1.f);
      float iou = inter / (a1 + a2 - inter);
      if (iou > 0.25f) sc[k] = -INFINITY;
    }
    if (tid == 0) sc[bi] = -INFINITY;
    __syncthreads();
  }
}

// ---- gather ---------------------------------------------------------------
__global__ void gather_kernel(const int* __restrict__ idx_i, const float* __restrict__ s_all,
                              float* __restrict__ boxes, float* __restrict__ out) {
  int t = blockIdx.x * blockDim.x + threadIdx.x;
  if (t >= 112) return;
  int b = t / 7;
  int w = idx_i[t];
  out[OFF_IDX + t] = (float)w;
  out[OFF_WSC + t] = s_all[b * 602 + w];
  float bb[4];
  win_to_box(w, bb);
#pragma unroll
  for (int k = 0; k < 4; ++k) {
    boxes[t * 4 + k] = bb[k];
    out[OFF_CRD + t * 4 + k] = bb[k];
  }
}

// ---- bilinear crop-resize 448 -> 112 --------------------------------------
__global__ void crop_resize_kernel(const float* __restrict__ x, const float* __restrict__ boxes,
                                   float* __restrict__ wimgs) {
  int idx = blockIdx.x * blockDim.x + threadIdx.x;
  const int total = 112 * 3 * 112 * 112;
  if (idx >= total) return;
  int j = idx % 112;
  int i = (idx / 112) % 112;
  int ch = (idx / (112 * 112)) % 3;
  int bp = idx / (3 * 112 * 112);
  int b = bp / 7;
  const float* bx = boxes + bp * 4;
  float t_i = (float)i / 111.0f;
  float t_j = (float)j / 111.0f;
  float rs = bx[0] + (bx[2] - bx[0]) * t_i;
  float cs = bx[1] + (bx[3] - bx[1]) * t_j;
  float r0f = floorf(rs), c0f = floorf(cs);
  float wr = rs - r0f, wc = cs - c0f;
  int r0 = (int)r0f, c0 = (int)c0f;
  int r1 = min(r0 + 1, 447), c1 = min(c0 + 1, 447);
  const float* img = x + ((size_t)b * 3 + ch) * 448 * 448;
  float v00 = img[r0 * 448 + c0], v01 = img[r0 * 448 + c1];
  float v10 = img[r1 * 448 + c0], v11 = img[r1 * 448 + c1];
  float top = (1.f - wc) * v00 + wc * v01;
  float bot = (1.f - wc) * v10 + wc * v11;
  wimgs[idx] = (1.f - wr) * top + wr * bot;
}

// ---- conv 3x3 stride2 SAME + bias + relu, CO4 channels per thread ---------
// One output pixel per thread, 4 co per thread. NO LDS, NO barriers:
// weights are read with wave-uniform indices -> scalar (SGPR) loads on the
// SMEM pipe; inputs use a 2-deep register prefetch (va/vb, const-indexed).
// grid.x = Cout/CO4 (fastest -> co-groups schedule-adjacent -> L2 input reuse)
// grid.y = cdiv(N*Hout*Wout, 256)
#define LOAD9(v, p)                                    \
  {                                                    \
    v[0] = (p)[0]; v[1] = (p)[1]; v[2] = (p)[2];       \
    v[3] = (p)[Win]; v[4] = (p)[Win + 1];              \
    v[5] = (p)[Win + 2]; v[6] = (p)[2 * Win];          \
    v[7] = (p)[2 * Win + 1]; v[8] = (p)[2 * Win + 2];  \
  }

#define FMAS(v, ci_)                                   \
  {                                                    \
    const float* w0_ = wr0 + (size_t)(ci_) * 9;        \
    const float* w1_ = wr1 + (size_t)(ci_) * 9;        \
    const float* w2_ = wr2 + (size_t)(ci_) * 9;        \
    const float* w3_ = wr3 + (size_t)(ci_) * 9;        \
    _Pragma("unroll") for (int k = 0; k < 9; ++k) {    \
      acc0 = fmaf(v[k], w0_[k], acc0);                 \
      acc1 = fmaf(v[k], w1_[k], acc1);                 \
      acc2 = fmaf(v[k], w2_[k], acc2);                 \
      acc3 = fmaf(v[k], w3_[k], acc3);                 \
    }                                                  \
  }

__global__ __launch_bounds__(256) void conv4_kernel(
    const float* __restrict__ in, const float* __restrict__ wt,
    const float* __restrict__ bias, float* __restrict__ out,
    int N, int Cin, int Hin, int Win, int Hout, int Wout, int pad) {
  const int co0 = blockIdx.x * CO4;
  const int Cout = gridDim.x * CO4;
  const int HW = Hout * Wout;
  const int total = N * HW;
  const int lin = blockIdx.y * 256 + threadIdx.x;
  if (lin >= total) return;  // no barriers in this kernel -> early exit safe
  const int n = lin / HW;
  const int pix = lin - n * HW;
  const int oh = pix / Wout, ow = pix - oh * Wout;
  const int ih0 = 2 * oh - pad, iw0 = 2 * ow - pad;
  const size_t inplane = (size_t)Hin * Win;
  const float* nbase = in + (size_t)n * Cin * inplane;
  const float* wr0 = wt + (size_t)co0 * Cin * 9;  // wave-uniform rows
  const float* wr1 = wr0 + (size_t)Cin * 9;
  const float* wr2 = wr1 + (size_t)Cin * 9;
  const float* wr3 = wr2 + (size_t)Cin * 9;

  float acc0 = 0.f, acc1 = 0.f, acc2 = 0.f, acc3 = 0.f;
  const bool interior = (ih0 >= 0) && (iw0 >= 0) && (ih0 + 2 < Hin) && (iw0 + 2 < Win);

  if (interior) {
    const float* base = nbase + (size_t)ih0 * Win + iw0;
    float va[9], vb[9];
    LOAD9(va, base);
    int ci = 0;
    for (; ci + 1 < Cin; ci += 2) {
      const float* p1 = base + (size_t)(ci + 1) * inplane;
      LOAD9(vb, p1);
      FMAS(va, ci);
      if (ci + 2 < Cin) {
        const float* p2 = base + (size_t)(ci + 2) * inplane;
        LOAD9(va, p2);
      }
      FMAS(vb, ci + 1);
    }
    if (ci < Cin) FMAS(va, ci);
  } else {
    for (int ci = 0; ci < Cin; ++ci) {
      const float* p = nbase + (size_t)ci * inplane;
      const float* w0_ = wr0 + (size_t)ci * 9;
      const float* w1_ = wr1 + (size_t)ci * 9;
      const float* w2_ = wr2 + (size_t)ci * 9;
      const float* w3_ = wr3 + (size_t)ci * 9;
#pragma unroll
      for (int kh = 0; kh < 3; ++kh) {
        int ih = ih0 + kh;
        if ((unsigned)ih >= (unsigned)Hin) continue;
#pragma unroll
        for (int kw = 0; kw < 3; ++kw) {
          int iw = iw0 + kw;
          if ((unsigned)iw >= (unsigned)Win) continue;
          float vv = p[(size_t)ih * Win + iw];
          int k = kh * 3 + kw;
          acc0 = fmaf(vv, w0_[k], acc0);
          acc1 = fmaf(vv, w1_[k], acc1);
          acc2 = fmaf(vv, w2_[k], acc2);
          acc3 = fmaf(vv, w3_[k], acc3);
        }
      }
    }
  }
  float* ob = out + ((size_t)n * Cout + co0) * HW + pix;
  ob[0] = fmaxf(acc0 + bias[co0 + 0], 0.f);
  ob[HW] = fmaxf(acc1 + bias[co0 + 1], 0.f);
  ob[2 * (size_t)HW] = fmaxf(acc2 + bias[co0 + 2], 0.f);
  ob[3 * (size_t)HW] = fmaxf(acc3 + bias[co0 + 3], 0.f);
}

// ---- mean pool ------------------------------------------------------------
__global__ void avgpool_kernel(const float* __restrict__ feat, float* __restrict__ pooled,
                               int M, int C, int S) {
  int idx = blockIdx.x * blockDim.x + threadIdx.x;
  if (idx >= M * C) return;
  const float* p = feat + (size_t)idx * S;
  float s = 0.f;
  for (int i = 0; i < S; ++i) s += p[i];
  pooled[idx] = s / (float)S;
}

// ---- head GEMM ------------------------------------------------------------
__global__ void head_kernel(const float* __restrict__ pooled, const float* __restrict__ hw,
                            const float* __restrict__ hb, float* __restrict__ outp, int M) {
  int idx = blockIdx.x * blockDim.x + threadIdx.x;
  if (idx >= M * 200) return;
  int m = idx / 200, c = idx - m * 200;
  float acc = hb[c];
  const float* pm = pooled + m * 512;
  for (int k = 0; k < 512; ++k) acc = fmaf(pm[k], hw[k * 200 + c], acc);
  outp[idx] = acc;
}

// ---------------------------------------------------------------------------
static void launch_conv4(const float* in, const float* wt, const float* bias, float* out,
                         int N, int Cin, int Hin, int Hout, int Cout, int pad, hipStream_t s) {
  int total = N * Hout * Hout;
  dim3 grid(Cout / CO4, cdiv(total, 256));
  conv4_kernel<<<grid, 256, 0, s>>>(in, wt, bias, out, N, Cin, Hin, Hin, Hout, Hout, pad);
}

extern "C" void kernel_launch(void* const* d_in, const int* in_sizes, int n_in,
                              void* d_out, int out_size, void* d_ws, size_t ws_size,
                              hipStream_t stream) {
  const float* x = (const float*)d_in[0];
  const float* att = (const float*)d_in[1];
  const float* W[5] = {(const float*)d_in[2], (const float*)d_in[4], (const float*)d_in[6],
                       (const float*)d_in[8], (const float*)d_in[10]};
  const float* Bv[5] = {(const float*)d_in[3], (const float*)d_in[5], (const float*)d_in[7],
                        (const float*)d_in[9], (const float*)d_in[11]};
  const float* head_w = (const float*)d_in[12];
  const float* head_b = (const float*)d_in[13];
  float* out = (float*)d_out;
  float* ws = (float*)d_ws;

  // workspace layout (floats), ~104MB (round-1 proven)
  size_t o = 0;
  float* s_all = ws + o;  o += 16 * 602;
  int* idx_i = (int*)(ws + o); o += 112;
  float* boxes = ws + o;  o += 112 * 4;
  float* wimgs = ws + o;  o += (size_t)112 * 3 * 112 * 112;
  float* featB = ws + o;  o += (size_t)16 * 512 * 196;
  float* featC = ws + o;  o += (size_t)112 * 512 * 16;
  float* pooled = ws + o; o += (size_t)112 * 512;
  float* bufA = ws + o;   o += (size_t)4 * 64 * 224 * 224;
  float* bufB = ws + o;   o += (size_t)4 * 128 * 112 * 112;

  // ---- proposal path ----
  winscores_kernel<<<cdiv(16 * 602, BS), BS, 0, stream>>>(att, s_all, out);
  nms_kernel<<<dim3(16, 2), 64, 0, stream>>>(s_all, idx_i);
  gather_kernel<<<1, 128, 0, stream>>>(idx_i, s_all, boxes, out);
  crop_resize_kernel<<<cdiv(112 * 3 * 112 * 112, BS), BS, 0, stream>>>(x, boxes, wimgs);

  // ---- big encoder: 4-image chunks ----
  for (int chunk = 0; chunk < 4; ++chunk) {
    int n0 = chunk * 4;
    const float* in0 = x + (size_t)n0 * 3 * 448 * 448;
    launch_conv4(in0, W[0], Bv[0], bufA, 4, 3, 448, 224, 64, 0, stream);
    launch_conv4(bufA, W[1], Bv[1], bufB, 4, 64, 224, 112, 128, 0, stream);
    launch_conv4(bufB, W[2], Bv[2], bufA, 4, 128, 112, 56, 256, 0, stream);
    launch_conv4(bufA, W[3], Bv[3], bufB, 4, 256, 56, 28, 512, 0, stream);
    launch_conv4(bufB, W[4], Bv[4], featB + (size_t)n0 * 512 * 196, 4, 512, 28, 14, 512, 0,
                 stream);
  }
  avgpool_kernel<<<cdiv(16 * 512, BS), BS, 0, stream>>>(featB, pooled, 16, 512, 196);
  head_kernel<<<cdiv(16 * 200, BS), BS, 0, stream>>>(pooled, head_w, head_b, out + OFF_LAB, 16);

  // ---- crop encoder: 56-crop chunks ----
  for (int chunk = 0; chunk < 2; ++chunk) {
    int c0 = chunk * 56;
    const float* in0 = wimgs + (size_t)c0 * 3 * 112 * 112;
    launch_conv4(in0, W[0], Bv[0], bufA, 56, 3, 112, 56, 64, 0, stream);
    launch_conv4(bufA, W[1], Bv[1], bufB, 56, 64, 56, 28, 128, 0, stream);
    launch_conv4(bufB, W[2], Bv[2], bufA, 56, 128, 28, 14, 256, 0, stream);
    launch_conv4(bufA, W[3], Bv[3], bufB, 56, 256, 14, 7, 512, 0, stream);
    launch_conv4(bufB, W[4], Bv[4], featC + (size_t)c0 * 512 * 16, 56, 512, 7, 4, 512, 1, stream);
  }
  avgpool_kernel<<<cdiv(112 * 512, BS), BS, 0, stream>>>(featC, pooled, 112, 512, 16);
  head_kernel<<<cdiv(112 * 200, BS), BS, 0, stream>>>(pooled, head_w, head_b, out + OFF_LOG, 112);
}

// Round 7
// 11884.224 us; speedup vs baseline: 1.4073x; 1.1874x over previous
//
#include <hip/hip_runtime.h>
#include <hip/hip_bf16.h>
#include <math.h>

// ---------------------------------------------------------------------------
// Classifier_with_Augmentation: NTS-Net-style pipeline.
//  outputs (flat float32 in d_out):
//   labels 16x200 @0 | win_scores 16x7 @3200 | win_logits 112x200 @3312
//   indices 16x7 @25712 | all_scores 16x602 @25824 | coordinates 16x7x4 @35456
// ---------------------------------------------------------------------------

#define OFF_LAB 0
#define OFF_WSC 3200
#define OFF_LOG 3312
#define OFF_IDX 25712
#define OFF_ALL 25824
#define OFF_CRD 35456

#define BS 256

static inline int cdiv(int a, int b) { return (a + b - 1) / b; }

// ---- window geometry ------------------------------------------------------
__device__ __forceinline__ void win_decode(int w, int& rh, int& rw, int& r, int& c) {
  const int RH[6] = {4, 3, 5, 6, 5, 7};
  const int RW[6] = {4, 5, 3, 6, 7, 5};
  int rem = w;
#pragma unroll
  for (int i = 0; i < 6; ++i) {
    int nc = 15 - RW[i];
    int cnt = (15 - RH[i]) * nc;
    if (rem < cnt) { rh = RH[i]; rw = RW[i]; r = rem / nc; c = rem - (rem / nc) * nc; return; }
    rem -= cnt;
  }
  rh = 4; rw = 4; r = 0; c = 0;
}

__device__ __forceinline__ void win_to_box(int w, float* bb) {
  int rh, rw, r, c;
  win_decode(w, rh, rw, r, c);
  bb[0] = r * 32.f;
  bb[1] = c * 32.f;
  bb[2] = (r + rh) * 32.f - 1.f;
  bb[3] = (c + rw) * 32.f - 1.f;
}

// ---- window scores --------------------------------------------------------
__global__ void winscores_kernel(const float* __restrict__ att, float* __restrict__ s_all,
                                 float* __restrict__ out) {
  int idx = blockIdx.x * blockDim.x + threadIdx.x;
  if (idx >= 16 * 602) return;
  int b = idx / 602, w = idx - b * 602;
  int rh, rw, r, c;
  win_decode(w, rh, rw, r, c);
  const float* a = att + b * 196;
  float s = 0.f;
  for (int dr = 0; dr < rh; ++dr)
    for (int dc = 0; dc < rw; ++dc)
      s += a[(r + dr) * 14 + (c + dc)];
  float v = s / (float)(rh * rw);
  s_all[idx] = v;
  out[OFF_ALL + idx] = v;
}

// ---- NMS: one wave per (batch, group) -------------------------------------
__global__ void nms_kernel(const float* __restrict__ s_all, int* __restrict__ idx_i) {
  const int b = blockIdx.x, g = blockIdx.y;
  const int gs = g ? 361 : 0;
  const int cnt = g ? 241 : 361;
  const int nsel = g ? 3 : 4;
  const int obase = b * 7 + (g ? 4 : 0);
  __shared__ float sc[361];
  __shared__ float bx0[361], bx1[361], bx2[361], bx3[361];
  const int tid = threadIdx.x;
  for (int k = tid; k < cnt; k += 64) {
    sc[k] = s_all[b * 602 + gs + k];
    float bb[4];
    win_to_box(gs + k, bb);
    bx0[k] = bb[0]; bx1[k] = bb[1]; bx2[k] = bb[2]; bx3[k] = bb[3];
  }
  __syncthreads();
  for (int it = 0; it < nsel; ++it) {
    float bv = -INFINITY;
    int bi = 0x7fffffff;
    for (int k = tid; k < cnt; k += 64) {
      float v = sc[k];
      if (v > bv || (v == bv && k < bi)) { bv = v; bi = k; }
    }
#pragma unroll
    for (int off = 32; off > 0; off >>= 1) {
      float ov = __shfl_down(bv, off);
      int oi = __shfl_down(bi, off);
      if (ov > bv || (ov == bv && oi < bi)) { bv = ov; bi = oi; }
    }
    bi = __shfl(bi, 0);
    if (tid == 0) idx_i[obase + it] = gs + bi;
    float X0 = bx0[bi], X1 = bx1[bi], X2 = bx2[bi], X3 = bx3[bi];
    float a1 = (X2 - X0 + 1.f) * (X3 - X1 + 1.f);
    __syncthreads();
    for (int k = tid; k < cnt; k += 64) {
      float x0 = fmaxf(X0, bx0[k]);
      float y0 = fmaxf(X1, bx1[k]);
      float x1 = fminf(X2, bx2[k]);
      float y1 = fminf(X3, bx3[k]);
      float inter = fmaxf(x1 - x0 + 1.f, 0.f) * fmaxf(y1 - y0 + 1.f, 0.f);
      float a2 = (bx2[k] - bx0[k] + 1.f) * (bx3[k] - bx1[k] + 1.f);
      float iou = inter / (a1 + a2 - inter);
      if (iou > 0.25f) sc[k] = -INFINITY;
    }
    if (tid == 0) sc[bi] = -INFINITY;
    __syncthreads();
  }
}

// ---- gather ---------------------------------------------------------------
__global__ void gather_kernel(const int* __restrict__ idx_i, const float* __restrict__ s_all,
                              float* __restrict__ boxes, float* __restrict__ out) {
  int t = blockIdx.x * blockDim.x + threadIdx.x;
  if (t >= 112) return;
  int b = t / 7;
  int w = idx_i[t];
  out[OFF_IDX + t] = (float)w;
  out[OFF_WSC + t] = s_all[b * 602 + w];
  float bb[4];
  win_to_box(w, bb);
#pragma unroll
  for (int k = 0; k < 4; ++k) {
    boxes[t * 4 + k] = bb[k];
    out[OFF_CRD + t * 4 + k] = bb[k];
  }
}

// ---- bilinear crop-resize 448 -> 112 --------------------------------------
__global__ void crop_resize_kernel(const float* __restrict__ x, const float* __restrict__ boxes,
                                   float* __restrict__ wimgs) {
  int idx = blockIdx.x * blockDim.x + threadIdx.x;
  const int total = 112 * 3 * 112 * 112;
  if (idx >= total) return;
  int j = idx % 112;
  int i = (idx / 112) % 112;
  int ch = (idx / (112 * 112)) % 3;
  int bp = idx / (3 * 112 * 112);
  int b = bp / 7;
  const float* bx = boxes + bp * 4;
  float t_i = (float)i / 111.0f;
  float t_j = (float)j / 111.0f;
  float rs = bx[0] + (bx[2] - bx[0]) * t_i;
  float cs = bx[1] + (bx[3] - bx[1]) * t_j;
  float r0f = floorf(rs), c0f = floorf(cs);
  float wr = rs - r0f, wc = cs - c0f;
  int r0 = (int)r0f, c0 = (int)c0f;
  int r1 = min(r0 + 1, 447), c1 = min(c0 + 1, 447);
  const float* img = x + ((size_t)b * 3 + ch) * 448 * 448;
  float v00 = img[r0 * 448 + c0], v01 = img[r0 * 448 + c1];
  float v10 = img[r1 * 448 + c0], v11 = img[r1 * 448 + c1];
  float top = (1.f - wc) * v00 + wc * v01;
  float bot = (1.f - wc) * v10 + wc * v11;
  wimgs[idx] = (1.f - wr) * top + wr * bot;
}

// ======================= KERNEL A: tile conv (big-spatial) ==================
// PIXT=4 pixels x 8 co per thread; weights in LDS [ci][k][co] (b128 broadcast).
// Round-2 inline structure (VGPR 68, no spill). Used for L0/L1 layers only
// (Win%4==0, pad=0, Wout%4==0).
__global__ __launch_bounds__(256, 2) void conv_t8_kernel(
    const float* __restrict__ in, const float* __restrict__ wt,
    const float* __restrict__ bias, float* __restrict__ out,
    int N, int Cin, int Hin, int Win, int Hout, int Wout, int pad) {
  const int Cout = gridDim.x * 8;
  const int co0 = blockIdx.x * 8;
  const int nTw = (Wout + 3) >> 2;
  const int tiles = N * Hout * nTw;
  const int lin = blockIdx.y * 256 + threadIdx.x;
  const bool active = lin < tiles;
  int tw = 0, oh = 0, n = 0;
  if (active) {
    tw = lin % nTw;
    int t2 = lin / nTw;
    oh = t2 % Hout;
    n = t2 / Hout;
  }
  const int owb = tw * 4;
  const int ih0 = 2 * oh - pad;
  const int iw0 = 2 * owb - pad;
  const size_t inplane = (size_t)Hin * Win;
  const float* nbase = in + (size_t)n * Cin * inplane;
  const bool r2ok = (ih0 + 2 < Hin);
  const bool c8ok = (iw0 + 8 < Win);
  const bool fullt = (owb + 3 < Wout);
  const bool fast = active && (ih0 >= 0) && (iw0 >= 0) && (iw0 + 7 < Win) && fullt;
  const bool vload = ((Win & 3) == 0) && (pad == 0);

  float acc[8][4];
#pragma unroll
  for (int j = 0; j < 8; ++j)
#pragma unroll
    for (int p = 0; p < 4; ++p) acc[j][p] = 0.f;

  __shared__ float w_lds[64 * 9 * 8];

  const int nchunk = (Cin + 63) >> 6;
  for (int ch = 0; ch < nchunk; ++ch) {
    const int ci0 = ch << 6;
    const int cich = min(64, Cin - ci0);
    const int nel = cich * 9;
    for (int t = threadIdx.x; t < nel * 8; t += 256) {
      int co = t / nel;
      int rem = t - co * nel;
      w_lds[rem * 8 + co] = wt[(size_t)(co0 + co) * Cin * 9 + (size_t)ci0 * 9 + rem];
    }
    __syncthreads();
    if (fast) {
      const float* pb = nbase + (size_t)ci0 * inplane + (size_t)ih0 * Win + iw0;
      for (int ci = 0; ci < cich; ++ci) {
        const float* p0 = pb + (size_t)ci * inplane;
        const float* p1 = p0 + Win;
        const float* p2 = p1 + Win;
        float rr[3][9];
        if (vload) {
          float4 a0 = *(const float4*)p0, b0 = *(const float4*)(p0 + 4);
          rr[0][0] = a0.x; rr[0][1] = a0.y; rr[0][2] = a0.z; rr[0][3] = a0.w;
          rr[0][4] = b0.x; rr[0][5] = b0.y; rr[0][6] = b0.z; rr[0][7] = b0.w;
          float4 a1 = *(const float4*)p1, b1 = *(const float4*)(p1 + 4);
          rr[1][0] = a1.x; rr[1][1] = a1.y; rr[1][2] = a1.z; rr[1][3] = a1.w;
          rr[1][4] = b1.x; rr[1][5] = b1.y; rr[1][6] = b1.z; rr[1][7] = b1.w;
          if (r2ok) {
            float4 a2 = *(const float4*)p2, b2 = *(const float4*)(p2 + 4);
            rr[2][0] = a2.x; rr[2][1] = a2.y; rr[2][2] = a2.z; rr[2][3] = a2.w;
            rr[2][4] = b2.x; rr[2][5] = b2.y; rr[2][6] = b2.z; rr[2][7] = b2.w;
          } else {
#pragma unroll
            for (int cc = 0; cc < 8; ++cc) rr[2][cc] = 0.f;
          }
        } else {
#pragma unroll
          for (int cc = 0; cc < 8; ++cc) rr[0][cc] = p0[cc];
#pragma unroll
          for (int cc = 0; cc < 8; ++cc) rr[1][cc] = p1[cc];
          if (r2ok) {
#pragma unroll
            for (int cc = 0; cc < 8; ++cc) rr[2][cc] = p2[cc];
          } else {
#pragma unroll
            for (int cc = 0; cc < 8; ++cc) rr[2][cc] = 0.f;
          }
        }
        rr[0][8] = c8ok ? p0[8] : 0.f;
        rr[1][8] = c8ok ? p1[8] : 0.f;
        rr[2][8] = (c8ok && r2ok) ? p2[8] : 0.f;
        const int b9 = ci * 9;
#pragma unroll
        for (int kh = 0; kh < 3; ++kh) {
#pragma unroll
          for (int kw = 0; kw < 3; ++kw) {
            const float* wp = &w_lds[(b9 + kh * 3 + kw) * 8];
            float4 wlo = *(const float4*)wp;
            float4 whi = *(const float4*)(wp + 4);
#pragma unroll
            for (int px = 0; px < 4; ++px) {
              float v = rr[kh][kw + 2 * px];
              acc[0][px] = fmaf(v, wlo.x, acc[0][px]);
              acc[1][px] = fmaf(v, wlo.y, acc[1][px]);
              acc[2][px] = fmaf(v, wlo.z, acc[2][px]);
              acc[3][px] = fmaf(v, wlo.w, acc[3][px]);
              acc[4][px] = fmaf(v, whi.x, acc[4][px]);
              acc[5][px] = fmaf(v, whi.y, acc[5][px]);
              acc[6][px] = fmaf(v, whi.z, acc[6][px]);
              acc[7][px] = fmaf(v, whi.w, acc[7][px]);
            }
          }
        }
      }
    } else if (active) {
      for (int ci = 0; ci < cich; ++ci) {
        const float* p = nbase + (size_t)(ci0 + ci) * inplane;
        const int b9 = ci * 9;
#pragma unroll
        for (int px = 0; px < 4; ++px) {
          int ow = owb + px;
          if (ow >= Wout) continue;
          int iwp = 2 * ow - pad;
#pragma unroll
          for (int kh = 0; kh < 3; ++kh) {
            int ih = ih0 + kh;
            if ((unsigned)ih >= (unsigned)Hin) continue;
#pragma unroll
            for (int kw = 0; kw < 3; ++kw) {
              int iw = iwp + kw;
              if ((unsigned)iw >= (unsigned)Win) continue;
              float v = p[(size_t)ih * Win + iw];
              const float* wp = &w_lds[(b9 + kh * 3 + kw) * 8];
#pragma unroll
              for (int j = 0; j < 8; ++j) acc[j][px] = fmaf(v, wp[j], acc[j][px]);
            }
          }
        }
      }
    }
    __syncthreads();
  }
  if (!active) return;
  const int HW = Hout * Wout;
  float* ob = out + ((size_t)n * Cout + co0) * HW + (size_t)oh * Wout + owb;
#pragma unroll
  for (int j = 0; j < 8; ++j) {
    float bj = bias[co0 + j];
    float* oj = ob + (size_t)j * HW;
    if (((Wout & 3) == 0) && fullt) {
      float4 v;
      v.x = fmaxf(acc[j][0] + bj, 0.f);
      v.y = fmaxf(acc[j][1] + bj, 0.f);
      v.z = fmaxf(acc[j][2] + bj, 0.f);
      v.w = fmaxf(acc[j][3] + bj, 0.f);
      *(float4*)oj = v;
    } else {
#pragma unroll
      for (int p = 0; p < 4; ++p)
        if (owb + p < Wout) oj[p] = fmaxf(acc[j][p] + bj, 0.f);
    }
  }
}

// ============ KERNEL B: per-pixel conv, scalar (SGPR) weights ===============
#define LOAD9(v, p)                                    \
  {                                                    \
    v[0] = (p)[0]; v[1] = (p)[1]; v[2] = (p)[2];       \
    v[3] = (p)[Win]; v[4] = (p)[Win + 1];              \
    v[5] = (p)[Win + 2]; v[6] = (p)[2 * Win];          \
    v[7] = (p)[2 * Win + 1]; v[8] = (p)[2 * Win + 2];  \
  }

// ---- CO=4 variant (crop L4) -- exact round-6 code --------------------------
#define FMAS4(v, ci_)                                  \
  {                                                    \
    const float* w0_ = wr0 + (size_t)(ci_) * 9;        \
    const float* w1_ = wr1 + (size_t)(ci_) * 9;        \
    const float* w2_ = wr2 + (size_t)(ci_) * 9;        \
    const float* w3_ = wr3 + (size_t)(ci_) * 9;        \
    _Pragma("unroll") for (int k = 0; k < 9; ++k) {    \
      acc0 = fmaf(v[k], w0_[k], acc0);                 \
      acc1 = fmaf(v[k], w1_[k], acc1);                 \
      acc2 = fmaf(v[k], w2_[k], acc2);                 \
      acc3 = fmaf(v[k], w3_[k], acc3);                 \
    }                                                  \
  }

__global__ __launch_bounds__(256) void conv4_kernel(
    const float* __restrict__ in, const float* __restrict__ wt,
    const float* __restrict__ bias, float* __restrict__ out,
    int N, int Cin, int Hin, int Win, int Hout, int Wout, int pad) {
  const int co0 = blockIdx.x * 4;
  const int Cout = gridDim.x * 4;
  const int HW = Hout * Wout;
  const int total = N * HW;
  const int lin = blockIdx.y * 256 + threadIdx.x;
  if (lin >= total) return;
  const int n = lin / HW;
  const int pix = lin - n * HW;
  const int oh = pix / Wout, ow = pix - oh * Wout;
  const int ih0 = 2 * oh - pad, iw0 = 2 * ow - pad;
  const size_t inplane = (size_t)Hin * Win;
  const float* nbase = in + (size_t)n * Cin * inplane;
  const float* wr0 = wt + (size_t)co0 * Cin * 9;
  const float* wr1 = wr0 + (size_t)Cin * 9;
  const float* wr2 = wr1 + (size_t)Cin * 9;
  const float* wr3 = wr2 + (size_t)Cin * 9;

  float acc0 = 0.f, acc1 = 0.f, acc2 = 0.f, acc3 = 0.f;
  const bool interior = (ih0 >= 0) && (iw0 >= 0) && (ih0 + 2 < Hin) && (iw0 + 2 < Win);

  if (interior) {
    const float* base = nbase + (size_t)ih0 * Win + iw0;
    float va[9], vb[9];
    LOAD9(va, base);
    int ci = 0;
    for (; ci + 1 < Cin; ci += 2) {
      const float* p1 = base + (size_t)(ci + 1) * inplane;
      LOAD9(vb, p1);
      FMAS4(va, ci);
      if (ci + 2 < Cin) {
        const float* p2 = base + (size_t)(ci + 2) * inplane;
        LOAD9(va, p2);
      }
      FMAS4(vb, ci + 1);
    }
    if (ci < Cin) FMAS4(va, ci);
  } else {
    for (int ci = 0; ci < Cin; ++ci) {
      const float* p = nbase + (size_t)ci * inplane;
      const float* w0_ = wr0 + (size_t)ci * 9;
      const float* w1_ = wr1 + (size_t)ci * 9;
      const float* w2_ = wr2 + (size_t)ci * 9;
      const float* w3_ = wr3 + (size_t)ci * 9;
#pragma unroll
      for (int kh = 0; kh < 3; ++kh) {
        int ih = ih0 + kh;
        if ((unsigned)ih >= (unsigned)Hin) continue;
#pragma unroll
        for (int kw = 0; kw < 3; ++kw) {
          int iw = iw0 + kw;
          if ((unsigned)iw >= (unsigned)Win) continue;
          float vv = p[(size_t)ih * Win + iw];
          int k = kh * 3 + kw;
          acc0 = fmaf(vv, w0_[k], acc0);
          acc1 = fmaf(vv, w1_[k], acc1);
          acc2 = fmaf(vv, w2_[k], acc2);
          acc3 = fmaf(vv, w3_[k], acc3);
        }
      }
    }
  }
  float* ob = out + ((size_t)n * Cout + co0) * HW + pix;
  ob[0] = fmaxf(acc0 + bias[co0 + 0], 0.f);
  ob[HW] = fmaxf(acc1 + bias[co0 + 1], 0.f);
  ob[2 * (size_t)HW] = fmaxf(acc2 + bias[co0 + 2], 0.f);
  ob[3 * (size_t)HW] = fmaxf(acc3 + bias[co0 + 3], 0.f);
}

// ---- CO=8 variant (deep small-spatial layers) ------------------------------
#define FMAS8(v, ci_)                                  \
  {                                                    \
    const float* w0_ = wr0 + (size_t)(ci_) * 9;        \
    const float* w1_ = w0_ + wstride;                  \
    const float* w2_ = w1_ + wstride;                  \
    const float* w3_ = w2_ + wstride;                  \
    const float* w4_ = w3_ + wstride;                  \
    const float* w5_ = w4_ + wstride;                  \
    const float* w6_ = w5_ + wstride;                  \
    const float* w7_ = w6_ + wstride;                  \
    _Pragma("unroll") for (int k = 0; k < 9; ++k) {    \
      acc0 = fmaf(v[k], w0_[k], acc0);                 \
      acc1 = fmaf(v[k], w1_[k], acc1);                 \
      acc2 = fmaf(v[k], w2_[k], acc2);                 \
      acc3 = fmaf(v[k], w3_[k], acc3);                 \
      acc4 = fmaf(v[k], w4_[k], acc4);                 \
      acc5 = fmaf(v[k], w5_[k], acc5);                 \
      acc6 = fmaf(v[k], w6_[k], acc6);                 \
      acc7 = fmaf(v[k], w7_[k], acc7);                 \
    }                                                  \
  }

__global__ __launch_bounds__(256) void conv8_kernel(
    const float* __restrict__ in, const float* __restrict__ wt,
    const float* __restrict__ bias, float* __restrict__ out,
    int N, int Cin, int Hin, int Win, int Hout, int Wout, int pad) {
  const int co0 = blockIdx.x * 8;
  const int Cout = gridDim.x * 8;
  const int HW = Hout * Wout;
  const int total = N * HW;
  const int lin = blockIdx.y * 256 + threadIdx.x;
  if (lin >= total) return;
  const int n = lin / HW;
  const int pix = lin - n * HW;
  const int oh = pix / Wout, ow = pix - oh * Wout;
  const int ih0 = 2 * oh - pad, iw0 = 2 * ow - pad;
  const size_t inplane = (size_t)Hin * Win;
  const size_t wstride = (size_t)Cin * 9;
  const float* nbase = in + (size_t)n * Cin * inplane;
  const float* wr0 = wt + (size_t)co0 * wstride;

  float acc0 = 0.f, acc1 = 0.f, acc2 = 0.f, acc3 = 0.f;
  float acc4 = 0.f, acc5 = 0.f, acc6 = 0.f, acc7 = 0.f;
  const bool interior = (ih0 >= 0) && (iw0 >= 0) && (ih0 + 2 < Hin) && (iw0 + 2 < Win);

  if (interior) {
    const float* base = nbase + (size_t)ih0 * Win + iw0;
    float va[9], vb[9];
    LOAD9(va, base);
    int ci = 0;
    for (; ci + 1 < Cin; ci += 2) {
      const float* p1 = base + (size_t)(ci + 1) * inplane;
      LOAD9(vb, p1);
      FMAS8(va, ci);
      if (ci + 2 < Cin) {
        const float* p2 = base + (size_t)(ci + 2) * inplane;
        LOAD9(va, p2);
      }
      FMAS8(vb, ci + 1);
    }
    if (ci < Cin) FMAS8(va, ci);
  } else {
    for (int ci = 0; ci < Cin; ++ci) {
      const float* p = nbase + (size_t)ci * inplane;
      const float* w0_ = wr0 + (size_t)ci * 9;
      const float* w1_ = w0_ + wstride;
      const float* w2_ = w1_ + wstride;
      const float* w3_ = w2_ + wstride;
      const float* w4_ = w3_ + wstride;
      const float* w5_ = w4_ + wstride;
      const float* w6_ = w5_ + wstride;
      const float* w7_ = w6_ + wstride;
#pragma unroll
      for (int kh = 0; kh < 3; ++kh) {
        int ih = ih0 + kh;
        if ((unsigned)ih >= (unsigned)Hin) continue;
#pragma unroll
        for (int kw = 0; kw < 3; ++kw) {
          int iw = iw0 + kw;
          if ((unsigned)iw >= (unsigned)Win) continue;
          float vv = p[(size_t)ih * Win + iw];
          int k = kh * 3 + kw;
          acc0 = fmaf(vv, w0_[k], acc0);
          acc1 = fmaf(vv, w1_[k], acc1);
          acc2 = fmaf(vv, w2_[k], acc2);
          acc3 = fmaf(vv, w3_[k], acc3);
          acc4 = fmaf(vv, w4_[k], acc4);
          acc5 = fmaf(vv, w5_[k], acc5);
          acc6 = fmaf(vv, w6_[k], acc6);
          acc7 = fmaf(vv, w7_[k], acc7);
        }
      }
    }
  }
  float* ob = out + ((size_t)n * Cout + co0) * HW + pix;
  ob[0] = fmaxf(acc0 + bias[co0 + 0], 0.f);
  ob[HW] = fmaxf(acc1 + bias[co0 + 1], 0.f);
  ob[2 * (size_t)HW] = fmaxf(acc2 + bias[co0 + 2], 0.f);
  ob[3 * (size_t)HW] = fmaxf(acc3 + bias[co0 + 3], 0.f);
  ob[4 * (size_t)HW] = fmaxf(acc4 + bias[co0 + 4], 0.f);
  ob[5 * (size_t)HW] = fmaxf(acc5 + bias[co0 + 5], 0.f);
  ob[6 * (size_t)HW] = fmaxf(acc6 + bias[co0 + 6], 0.f);
  ob[7 * (size_t)HW] = fmaxf(acc7 + bias[co0 + 7], 0.f);
}

// ---- mean pool ------------------------------------------------------------
__global__ void avgpool_kernel(const float* __restrict__ feat, float* __restrict__ pooled,
                               int M, int C, int S) {
  int idx = blockIdx.x * blockDim.x + threadIdx.x;
  if (idx >= M * C) return;
  const float* p = feat + (size_t)idx * S;
  float s = 0.f;
  for (int i = 0; i < S; ++i) s += p[i];
  pooled[idx] = s / (float)S;
}

// ---- head GEMM ------------------------------------------------------------
__global__ void head_kernel(const float* __restrict__ pooled, const float* __restrict__ hw,
                            const float* __restrict__ hb, float* __restrict__ outp, int M) {
  int idx = blockIdx.x * blockDim.x + threadIdx.x;
  if (idx >= M * 200) return;
  int m = idx / 200, c = idx - m * 200;
  float acc = hb[c];
  const float* pm = pooled + m * 512;
  for (int k = 0; k < 512; ++k) acc = fmaf(pm[k], hw[k * 200 + c], acc);
  outp[idx] = acc;
}

// ---------------------------------------------------------------------------
static void launch_A(const float* in, const float* wt, const float* bias, float* out,
                     int N, int Cin, int Hin, int Hout, int Cout, hipStream_t s) {
  int nTw = (Hout + 3) >> 2;
  int tiles = N * Hout * nTw;
  dim3 grid(Cout / 8, cdiv(tiles, 256));
  conv_t8_kernel<<<grid, 256, 0, s>>>(in, wt, bias, out, N, Cin, Hin, Hin, Hout, Hout, 0);
}

static void launch_B8(const float* in, const float* wt, const float* bias, float* out,
                      int N, int Cin, int Hin, int Hout, int Cout, int pad, hipStream_t s) {
  int total = N * Hout * Hout;
  dim3 grid(Cout / 8, cdiv(total, 256));
  conv8_kernel<<<grid, 256, 0, s>>>(in, wt, bias, out, N, Cin, Hin, Hin, Hout, Hout, pad);
}

static void launch_B4(const float* in, const float* wt, const float* bias, float* out,
                      int N, int Cin, int Hin, int Hout, int Cout, int pad, hipStream_t s) {
  int total = N * Hout * Hout;
  dim3 grid(Cout / 4, cdiv(total, 256));
  conv4_kernel<<<grid, 256, 0, s>>>(in, wt, bias, out, N, Cin, Hin, Hin, Hout, Hout, pad);
}

extern "C" void kernel_launch(void* const* d_in, const int* in_sizes, int n_in,
                              void* d_out, int out_size, void* d_ws, size_t ws_size,
                              hipStream_t stream) {
  const float* x = (const float*)d_in[0];
  const float* att = (const float*)d_in[1];
  const float* W[5] = {(const float*)d_in[2], (const float*)d_in[4], (const float*)d_in[6],
                       (const float*)d_in[8], (const float*)d_in[10]};
  const float* Bv[5] = {(const float*)d_in[3], (const float*)d_in[5], (const float*)d_in[7],
                        (const float*)d_in[9], (const float*)d_in[11]};
  const float* head_w = (const float*)d_in[12];
  const float* head_b = (const float*)d_in[13];
  float* out = (float*)d_out;
  float* ws = (float*)d_ws;

  // workspace layout (floats), ~130MB (round-3 proven)
  size_t o = 0;
  float* s_all = ws + o;  o += 16 * 602;
  int* idx_i = (int*)(ws + o); o += 112;
  float* boxes = ws + o;  o += 112 * 4;
  float* wimgs = ws + o;  o += (size_t)112 * 3 * 112 * 112;
  float* featB = ws + o;  o += (size_t)16 * 512 * 196;
  float* featC = ws + o;  o += (size_t)112 * 512 * 16;
  float* pooled = ws + o; o += (size_t)112 * 512;
  float* featL3 = ws + o; o += (size_t)16 * 512 * 784;  // L3 out (both encoders)
  float* bufA = ws + o;   o += (size_t)4 * 64 * 224 * 224;
  float* bufB = ws + o;   o += (size_t)4 * 128 * 112 * 112;

  // ---- proposal path ----
  winscores_kernel<<<cdiv(16 * 602, BS), BS, 0, stream>>>(att, s_all, out);
  nms_kernel<<<dim3(16, 2), 64, 0, stream>>>(s_all, idx_i);
  gather_kernel<<<1, 128, 0, stream>>>(idx_i, s_all, boxes, out);
  crop_resize_kernel<<<cdiv(112 * 3 * 112 * 112, BS), BS, 0, stream>>>(x, boxes, wimgs);

  // ---- big encoder: L0-L3 in 4-image chunks, L4 over all 16 ----
  for (int chunk = 0; chunk < 4; ++chunk) {
    int n0 = chunk * 4;
    const float* in0 = x + (size_t)n0 * 3 * 448 * 448;
    launch_A(in0, W[0], Bv[0], bufA, 4, 3, 448, 224, 64, stream);            // 1568 blk
    launch_A(bufA, W[1], Bv[1], bufB, 4, 64, 224, 112, 128, stream);         // 784 blk
    launch_B8(bufB, W[2], Bv[2], bufA, 4, 128, 112, 56, 256, 0, stream);     // 1568 blk
    launch_B8(bufA, W[3], Bv[3], featL3 + (size_t)n0 * 512 * 784, 4, 256, 56, 28, 512, 0,
              stream);                                                        // 832 blk
  }
  launch_B8(featL3, W[4], Bv[4], featB, 16, 512, 28, 14, 512, 0, stream);    // 832 blk
  avgpool_kernel<<<cdiv(16 * 512, BS), BS, 0, stream>>>(featB, pooled, 16, 512, 196);
  head_kernel<<<cdiv(16 * 200, BS), BS, 0, stream>>>(pooled, head_w, head_b, out + OFF_LAB, 16);

  // ---- crop encoder: L0-L3 in 56-crop chunks, L4 over all 112 ----
  for (int chunk = 0; chunk < 2; ++chunk) {
    int c0 = chunk * 56;
    const float* in0 = wimgs + (size_t)c0 * 3 * 112 * 112;
    launch_A(in0, W[0], Bv[0], bufA, 56, 3, 112, 56, 64, stream);            // 1376 blk
    launch_A(bufA, W[1], Bv[1], bufB, 56, 64, 56, 28, 128, stream);          // 688 blk
    launch_B8(bufB, W[2], Bv[2], bufA, 56, 128, 28, 14, 256, 0, stream);     // 1376 blk
    launch_B8(bufA, W[3], Bv[3], featL3 + (size_t)c0 * 512 * 49, 56, 256, 14, 7, 512, 0,
              stream);                                                        // 704 blk
  }
  launch_B4(featL3, W[4], Bv[4], featC, 112, 512, 7, 4, 512, 1, stream);     // 896 blk
  avgpool_kernel<<<cdiv(112 * 512, BS), BS, 0, stream>>>(featC, pooled, 112, 512, 16);
  head_kernel<<<cdiv(112 * 200, BS), BS, 0, stream>>>(pooled, head_w, head_b, out + OFF_LOG, 112);
}